// Round 11
// baseline (317.328 us; speedup 1.0000x reference)
//
#include <hip/hip_runtime.h>
#include <hip/hip_bf16.h>

#define T_SEQ 2048
#define D_MODEL 2048
#define NH 16
#define NKVH 4
#define HD 128

typedef __attribute__((ext_vector_type(8))) short bf16x8;
typedef __attribute__((ext_vector_type(4))) float f32x4;

static __device__ __forceinline__ short f32_to_bf16(float f) {
    unsigned u = __float_as_uint(f);
    u += 0x7fffu + ((u >> 16) & 1u);
    return (short)(u >> 16);
}
static __device__ __forceinline__ float bf16_to_f32(short s) {
    return __uint_as_float(((unsigned)(unsigned short)s) << 16);
}
static __device__ __forceinline__ void gl_to_lds16(const void* g, void* l) {
    __builtin_amdgcn_global_load_lds(
        (const __attribute__((address_space(1))) unsigned int*)g,
        (__attribute__((address_space(3))) unsigned int*)l, 16, 0, 0);
}

// ---------------------------------------------------------------------------
// Pipelined GEMM: R7 version verbatim (in best-measured 305.5 total).
// BM=64, 256 thr, 512 blocks = 2/CU; tbuf + counted vmcnt.
// R8: BM=128 @ 1/CU lost 23us. R9 lesson (attn): never per-lane-scatter
// L2 reads for MFMA fragments -- stage via global_load_lds.
// ---------------------------------------------------------------------------
template<int BN>
__global__ __launch_bounds__(256, 2) void gemm_bt_kernel(
    const short* __restrict__ A, const short* __restrict__ Bt,
    float* __restrict__ Cf, short* __restrict__ Cb,
    int M, int N, int K, const float* __restrict__ bias, int act)
{
    constexpr int NI = BN / 64;                // 2 or 1
    constexpr int BCH = BN / 32;               // B staging instrs/wave (4 or 2)
    __shared__ short Alds[3][64 * 64];
    __shared__ short Blds[3][BN * 64];

    const int tid = threadIdx.x;
    const int wave = tid >> 6, lane = tid & 63;
    const int l16 = lane & 15, quad = lane >> 4;
    const int wn = wave * (BN / 4);
    const int m0 = blockIdx.y * 64, n0 = blockIdx.x * BN;
    const int niter = K >> 6;

    f32x4 acc[4][NI] = {};

    #pragma unroll
    for (int st = 0; st < 2; ++st) {
        int kk0 = st << 6;
        #pragma unroll
        for (int p = 0; p < 2; ++p) {
            int li = p * 256 + tid;
            int row = li >> 3, sc = li & 7;
            gl_to_lds16(A + (size_t)(m0 + row) * K + kk0 + ((sc ^ (row & 7)) * 8),
                        &Alds[st][(size_t)(p * 256 + wave * 64) * 8]);
        }
        #pragma unroll
        for (int p = 0; p < BCH; ++p) {
            int li = p * 256 + tid;
            int row = li >> 3, sc = li & 7;
            gl_to_lds16(Bt + (size_t)(n0 + row) * K + kk0 + ((sc ^ (row & 7)) * 8),
                        &Blds[st][(size_t)(p * 256 + wave * 64) * 8]);
        }
    }

    int cur = 0, stg = 2;
    for (int t = 0; t < niter; ++t) {
        if (t + 1 < niter) {
            if constexpr (BN == 128)
                asm volatile("s_waitcnt vmcnt(6)\n\ts_barrier" ::: "memory");
            else
                asm volatile("s_waitcnt vmcnt(4)\n\ts_barrier" ::: "memory");
        } else {
            asm volatile("s_waitcnt vmcnt(0)\n\ts_barrier" ::: "memory");
        }

        if (t + 2 < niter) {
            int k1 = (t + 2) << 6;
            #pragma unroll
            for (int p = 0; p < 2; ++p) {
                int li = p * 256 + tid;
                int row = li >> 3, sc = li & 7;
                gl_to_lds16(A + (size_t)(m0 + row) * K + k1 + ((sc ^ (row & 7)) * 8),
                            &Alds[stg][(size_t)(p * 256 + wave * 64) * 8]);
            }
            #pragma unroll
            for (int p = 0; p < BCH; ++p) {
                int li = p * 256 + tid;
                int row = li >> 3, sc = li & 7;
                gl_to_lds16(Bt + (size_t)(n0 + row) * K + k1 + ((sc ^ (row & 7)) * 8),
                            &Blds[stg][(size_t)(p * 256 + wave * 64) * 8]);
            }
        }

        const short* Ab = Alds[cur];
        const short* Bb = Blds[cur];
        #pragma unroll
        for (int kk = 0; kk < 2; ++kk) {
            bf16x8 a[4], b[NI];
            #pragma unroll
            for (int i = 0; i < 4; ++i)
                a[i] = *(const bf16x8*)
                    &Ab[(size_t)(i * 16 + l16) * 64 + (((kk * 4 + quad) ^ (l16 & 7)) * 8)];
            #pragma unroll
            for (int i = 0; i < NI; ++i)
                b[i] = *(const bf16x8*)
                    &Bb[(size_t)(wn + i * 16 + l16) * 64 + (((kk * 4 + quad) ^ (l16 & 7)) * 8)];
            #pragma unroll
            for (int mi = 0; mi < 4; ++mi)
                #pragma unroll
                for (int ni = 0; ni < NI; ++ni)
                    acc[mi][ni] = __builtin_amdgcn_mfma_f32_16x16x32_bf16(
                        a[mi], b[ni], acc[mi][ni], 0, 0, 0);
        }
        cur = (cur == 2) ? 0 : cur + 1;
        stg = (stg == 2) ? 0 : stg + 1;
    }

    #pragma unroll
    for (int mi = 0; mi < 4; ++mi) {
        #pragma unroll
        for (int ni = 0; ni < NI; ++ni) {
            int col = n0 + wn + ni * 16 + l16;
            float bv = bias ? bias[col] : 0.0f;
            #pragma unroll
            for (int r = 0; r < 4; ++r) {
                int row = m0 + mi * 16 + quad * 4 + r;
                float x = acc[mi][ni][r] + bv;
                if (act) x = x / (1.0f + __expf(-x));
                size_t o = (size_t)row * N + col;
                if (Cf) Cf[o] = x;
                if (Cb) Cb[o] = f32_to_bf16(x);
            }
        }
    }
}

// ---------------------------------------------------------------------------
// prep R11: weight transposes + EMA in ONE launch (R10 lesson: each launch
// gap ~2-3us). Blocks [0,12288): transpose (flattened 192 x 64 grid);
// [12288,12416): EMA (16 t-blocks x 8 d-blocks, 256 thr). Independent ops;
// combined grid keeps all CUs fed (solves ema's half-coverage standalone).
// ---------------------------------------------------------------------------
__global__ __launch_bounds__(256) void prep_kernel(
    const float* __restrict__ Wq, const float* __restrict__ Wk,
    const float* __restrict__ Wv, const float* __restrict__ Wr1,
    const float* __restrict__ Wo, const float* __restrict__ hs,
    short* __restrict__ Wq_t, short* __restrict__ Wkv_t,
    short* __restrict__ Wr1_t, short* __restrict__ Wo_t,
    float* __restrict__ l2, short* __restrict__ hs_b)
{
    __shared__ float tile[32][33];
    int b = blockIdx.x;
    if (b < 12288) {                       // ---- weight transposes ----
        int j = b / 192, bx = b - j * 192;
        const float* src; short* dst; int ld, cb;
        if (bx < 64)       { src = Wq;  dst = Wq_t;  ld = 2048; cb = bx; }
        else if (bx < 80)  { src = Wk;  dst = Wkv_t; ld = 512;  cb = bx - 64; }
        else if (bx < 96)  { src = Wv;  dst = Wkv_t + (size_t)512 * 2048; ld = 512; cb = bx - 80; }
        else if (bx < 128) { src = Wr1; dst = Wr1_t; ld = 1024; cb = bx - 96; }
        else               { src = Wo;  dst = Wo_t;  ld = 2048; cb = bx - 128; }
        int c0 = cb * 32, r0 = j * 32;
        int t = threadIdx.x;
        int r = t >> 3, c4 = (t & 7) * 4;
        float4 v = *(const float4*)&src[(size_t)(r0 + r) * ld + c0 + c4];
        tile[r][c4 + 0] = v.x; tile[r][c4 + 1] = v.y;
        tile[r][c4 + 2] = v.z; tile[r][c4 + 3] = v.w;
        __syncthreads();
        short o[4];
        #pragma unroll
        for (int q = 0; q < 4; ++q) o[q] = f32_to_bf16(tile[c4 + q][r]);
        *(uint2*)&dst[(size_t)(c0 + r) * 2048 + r0 + c4] = *(const uint2*)o;
    } else {                               // ---- windowed causal EMA ----
        int eb = b - 12288;
        int d = (eb >> 4) * 256 + threadIdx.x;
        int t0 = (eb & 15) * 128;
        int ts = t0 - 192; if (ts < 0) ts = 0;
        float m = 0.0f;
        for (int tb = ts; tb < t0; tb += 16) {
            float buf[16];
            #pragma unroll
            for (int j = 0; j < 16; ++j) buf[j] = hs[(size_t)(tb + j) * D_MODEL + d];
            #pragma unroll
            for (int j = 0; j < 16; ++j) m = 0.9f * m + 0.1f * buf[j];
        }
        for (int tb = t0; tb < t0 + 128; tb += 16) {
            float buf[16];
            #pragma unroll
            for (int j = 0; j < 16; ++j) buf[j] = hs[(size_t)(tb + j) * D_MODEL + d];
            #pragma unroll
            for (int j = 0; j < 16; ++j) hs_b[(size_t)(tb + j) * D_MODEL + d] = f32_to_bf16(buf[j]);
            #pragma unroll
            for (int j = 0; j < 16; ++j) { m = 0.9f * m + 0.1f * buf[j]; buf[j] = m; }
            #pragma unroll
            for (int j = 0; j < 16; ++j) l2[(size_t)(tb + j) * D_MODEL + d] = buf[j];
        }
    }
}

// ---------------------------------------------------------------------------
// fuse: router head folded in (R10). grid 4096 x 256thr.
// ---------------------------------------------------------------------------
__global__ __launch_bounds__(256) void fuse_kernel(
    const float* __restrict__ hs, const float* __restrict__ l2,
    const short* __restrict__ h, const float* __restrict__ Wr2,
    const float* __restrict__ br2, short* __restrict__ fused)
{
    const int tid = threadIdx.x;
    const int t = blockIdx.x >> 1;

    float z0 = 0.0f, z1 = 0.0f;
    {
        const short* hr = h + (size_t)t * 1024;
        short4 hv4 = *(const short4*)&hr[tid * 4];
        const float2* w2 = (const float2*)Wr2;
        #pragma unroll
        for (int j = 0; j < 4; ++j) {
            float hv = bf16_to_f32(((const short*)&hv4)[j]);
            float2 w = w2[tid * 4 + j];
            z0 += hv * w.x;
            z1 += hv * w.y;
        }
    }
    #pragma unroll
    for (int off = 1; off < 64; off <<= 1) {
        z0 += __shfl_xor(z0, off);
        z1 += __shfl_xor(z1, off);
    }
    __shared__ float red[2][4];
    int wave = tid >> 6, lane = tid & 63;
    if (lane == 0) { red[0][wave] = z0; red[1][wave] = z1; }
    __syncthreads();
    z0 = red[0][0] + red[0][1] + red[0][2] + red[0][3] + br2[0];
    z1 = red[1][0] + red[1][1] + red[1][2] + red[1][3] + br2[1];
    float mx = fmaxf(z0, z1);
    float e0 = expf(z0 - mx), e1 = expf(z1 - mx);
    float inv = 1.0f / (e0 + e1);
    float a0 = e0 * inv, a1 = e1 * inv;

    int idx = blockIdx.x * 256 + tid;
    float4 a = ((const float4*)hs)[idx];
    float4 b = ((const float4*)l2)[idx];
    short o[4] = {f32_to_bf16(a0 * a.x + a1 * b.x), f32_to_bf16(a0 * a.y + a1 * b.y),
                  f32_to_bf16(a0 * a.z + a1 * b.z), f32_to_bf16(a0 * a.w + a1 * b.w)};
    *(uint2*)(fused + (size_t)idx * 4) = *(const uint2*)o;
}

// ---------------------------------------------------------------------------
// rope_q + rope_k + V-transpose in one launch (R10).
// ---------------------------------------------------------------------------
__global__ __launch_bounds__(256) void pp_kernel(
    const short* __restrict__ q, const short* __restrict__ kv,
    short* __restrict__ qr, short* __restrict__ kr, short* __restrict__ vr)
{
    int bx = blockIdx.x;
    if (bx < 8192) {                       // RoPE q, 1/sqrt(HD) folded in
        int idx = bx * 256 + threadIdx.x;
        int d = idx & 63;
        int h = (idx >> 6) & 15;
        int t = idx >> 10;
        float fr = (float)t * __expf(-(float)d * 0.14391156831212787f);
        float s, c;
        sincosf(fr, &s, &c);
        const float sc = 0.08838834764831845f;
        const short* src = q + (size_t)t * D_MODEL + h * HD;
        float x1 = bf16_to_f32(src[d]) * sc, x2 = bf16_to_f32(src[d + 64]) * sc;
        short* dst = qr + ((size_t)h * T_SEQ + t) * HD;
        dst[d]      = f32_to_bf16(x1 * c - x2 * s);
        dst[d + 64] = f32_to_bf16(x2 * c + x1 * s);
    } else if (bx < 10240) {               // RoPE k
        int idx = (bx - 8192) * 256 + threadIdx.x;
        int d = idx & 63;
        int kh = (idx >> 6) & 3;
        int t = idx >> 8;
        float fr = (float)t * __expf(-(float)d * 0.14391156831212787f);
        float s, c;
        sincosf(fr, &s, &c);
        const short* src = kv + (size_t)t * 1024 + kh * HD;
        float x1 = bf16_to_f32(src[d]), x2 = bf16_to_f32(src[d + 64]);
        short* dst = kr + ((size_t)kh * T_SEQ + t) * HD;
        dst[d]      = f32_to_bf16(x1 * c - x2 * s);
        dst[d + 64] = f32_to_bf16(x2 * c + x1 * s);
    } else {                               // bf16 transpose of v half of kv
        __shared__ float tile[32][33];
        int b2 = bx - 10240;
        int c0 = (b2 & 15) * 32, r0 = (b2 >> 4) * 32;
        const short* src = kv + 512;
        int x = threadIdx.x & 31, y = threadIdx.x >> 5;
        #pragma unroll
        for (int i = 0; i < 4; ++i)
            tile[y + i * 8][x] = bf16_to_f32(src[(size_t)(r0 + y + i * 8) * 1024 + c0 + x]);
        __syncthreads();
        #pragma unroll
        for (int i = 0; i < 4; ++i)
            vr[(size_t)(c0 + y + i * 8) * 2048 + r0 + x] = f32_to_bf16(tile[x][y + i * 8]);
    }
}

// ---------------------------------------------------------------------------
// Causal flash attention R11 = R7/R10 shell + SPLIT-WAIT counted vmcnt.
// The single vmcnt(0) at iter top forced both K(t) AND V(t) (64KB of L2
// transfer, ~1100+cy) resident before any compute, though V isn't consumed
// until after the softmax (~1500cy later). Split: top vmcnt(4) [K ready,
// V's 4 loads still in flight] -> barrier -> prefetch -> QK -> softmax ->
// vmcnt(8)+lgkmcnt(0) [V ready; next stage's 8 loads stay in flight --
// never drained to 0 in steady state] -> barrier -> PV. V-frag reads are
// back after the V-barrier (R10's hoist read Vb before V was guaranteed).
// R9 lesson: K/V must be LDS-staged. P padded [32][40].
// ---------------------------------------------------------------------------
__global__ __launch_bounds__(512, 2) void attn_kernel(
    const short* __restrict__ Qr, const short* __restrict__ Kr,
    const short* __restrict__ Vt, short* __restrict__ Out)
{
    const int h = blockIdx.x;           // 0..15  (fast dim -> XCD spread)
    const int y = blockIdx.y;           // 0..15, pair index
    const int kvh = h >> 2;
    const int tid = threadIdx.x;
    const int wave = tid >> 6, lane = tid & 63;
    const int l16 = lane & 15, quad = lane >> 4;
    const int wq = wave & 1;            // q-subset (32 rows)
    const int wk = wave >> 1;           // kv-quarter (32 cols)

    __shared__ __align__(16) char smem[151552];
    short* Klds = (short*)smem;               // [2][128*128]  64 KB
    short* Vlds = (short*)(smem + 65536);     // [2][128*128]  64 KB
    short* Plds = (short*)(smem + 131072);    // [8][32][40]   20 KB, padded

    const short* kbase = Kr + (size_t)kvh * T_SEQ * HD;
    const short* vbase = Vt + (size_t)kvh * HD * T_SEQ;

    #pragma unroll 1
    for (int ph = 0; ph < 2; ++ph) {
        const int qt32 = ph ? (31 - y) : y;        // 64-row tile index
        const int qbase = qt32 * 64 + wq * 32;
        const int n = (qt32 >> 1) + 1;             // KV-128 tiles needed
        const int ko = wk * 32;                    // this wave's kv-quarter

        bf16x8 qf[2][4];
        #pragma unroll
        for (int m = 0; m < 2; ++m) {
            const short* qrow = Qr + ((size_t)h * T_SEQ + qbase + m * 16 + l16) * HD;
            #pragma unroll
            for (int kc = 0; kc < 4; ++kc)
                qf[m][kc] = *(const bf16x8*)&qrow[kc * 32 + quad * 8];
        }
        f32x4 o[2][8] = {};
        float lsum[2][4] = {};

        __syncthreads();   // LDS free (ph0: init; ph1: merge readers done)

        {   // stage tile 0 -> buf 0 (4 K + 4 V loads per thread)
            #pragma unroll
            for (int p = 0; p < 4; ++p) {
                int li = p * 512 + tid;
                int row = li >> 4, gs = (li & 15) ^ (row & 15);
                gl_to_lds16(kbase + (size_t)row * HD + gs * 8,
                            &Klds[(size_t)(p * 512 + wave * 64) * 8]);
            }
            #pragma unroll
            for (int p = 0; p < 4; ++p) {
                int li = p * 512 + tid;
                int row = li >> 4, gs = (li & 15) ^ (row & 15);
                gl_to_lds16(vbase + (size_t)row * T_SEQ + gs * 8,
                            &Vlds[(size_t)(p * 512 + wave * 64) * 8]);
            }
        }

        for (int t = 0; t < n; ++t) {
            // K(t) ready globally; V(t)'s 4 loads may remain in flight
            asm volatile("s_waitcnt vmcnt(4)\n\ts_barrier" ::: "memory");

            if (t + 1 < n) {   // prefetch next KV-128 tile (4 K + 4 V)
                int kv1 = (t + 1) << 7;
                int nb = (t + 1) & 1;
                const short* ks = kbase + (size_t)kv1 * HD;
                #pragma unroll
                for (int p = 0; p < 4; ++p) {
                    int li = p * 512 + tid;
                    int row = li >> 4, gs = (li & 15) ^ (row & 15);
                    gl_to_lds16(ks + (size_t)row * HD + gs * 8,
                                &Klds[(size_t)(nb * 16384 + (p * 512 + wave * 64) * 8)]);
                }
                #pragma unroll
                for (int p = 0; p < 4; ++p) {
                    int li = p * 512 + tid;
                    int row = li >> 4, gs = (li & 15) ^ (row & 15);
                    gl_to_lds16(vbase + (size_t)row * T_SEQ + kv1 + gs * 8,
                                &Vlds[(size_t)(nb * 16384 + (p * 512 + wave * 64) * 8)]);
                }
            }

            const short* Kb = Klds + (size_t)(t & 1) * 16384;
            const short* Vb = Vlds + (size_t)(t & 1) * 16384;

            // QK^T: 32 q-rows x this wave's 32 kv cols
            f32x4 s[2][2];
            #pragma unroll
            for (int m = 0; m < 2; ++m)
                #pragma unroll
                for (int ni = 0; ni < 2; ++ni) s[m][ni] = (f32x4){0, 0, 0, 0};
            __builtin_amdgcn_s_setprio(1);
            #pragma unroll
            for (int ni = 0; ni < 2; ++ni)
                #pragma unroll
                for (int kc = 0; kc < 4; ++kc) {
                    bf16x8 b = *(const bf16x8*)
                        &Kb[(size_t)(ko + ni * 16 + l16) * 128 + (((kc * 4 + quad) ^ l16) * 8)];
                    s[0][ni] = __builtin_amdgcn_mfma_f32_16x16x32_bf16(qf[0][kc], b, s[0][ni], 0, 0, 0);
                    s[1][ni] = __builtin_amdgcn_mfma_f32_16x16x32_bf16(qf[1][kc], b, s[1][ni], 0, 0, 0);
                }
            __builtin_amdgcn_s_setprio(0);

            // softmax (max-free) -> padded P [32][40]
            short* Pw = Plds + wave * 1280;
            if (t == n - 1) {
                int kvg0 = (t << 7) + ko;
                #pragma unroll
                for (int m = 0; m < 2; ++m)
                    #pragma unroll
                    for (int ni = 0; ni < 2; ++ni) {
                        int kvg = kvg0 + ni * 16 + l16;
                        #pragma unroll
                        for (int r = 0; r < 4; ++r) {
                            int qg = qbase + m * 16 + quad * 4 + r;
                            float p = (kvg <= qg) ? __expf(s[m][ni][r]) : 0.0f;
                            lsum[m][r] += p;
                            Pw[(m * 16 + quad * 4 + r) * 40 + ni * 16 + l16] =
                                f32_to_bf16(p);
                        }
                    }
            } else {
                #pragma unroll
                for (int m = 0; m < 2; ++m)
                    #pragma unroll
                    for (int ni = 0; ni < 2; ++ni)
                        #pragma unroll
                        for (int r = 0; r < 4; ++r) {
                            float p = __expf(s[m][ni][r]);
                            lsum[m][r] += p;
                            Pw[(m * 16 + quad * 4 + r) * 40 + ni * 16 + l16] =
                                f32_to_bf16(p);
                        }
            }

            // V(t) ready globally + own P visible; counted in steady state
            if (t + 1 < n)
                asm volatile("s_waitcnt vmcnt(8) lgkmcnt(0)\n\ts_barrier" ::: "memory");
            else
                asm volatile("s_waitcnt vmcnt(0) lgkmcnt(0)\n\ts_barrier" ::: "memory");

            // PV: V-frag reads (post-barrier) feed 2 row-groups
            __builtin_amdgcn_s_setprio(1);
            {
                bf16x8 pa0 = *(const bf16x8*)&Pw[l16 * 40 + quad * 8];
                bf16x8 pa1 = *(const bf16x8*)&Pw[(16 + l16) * 40 + quad * 8];
                #pragma unroll
                for (int d8 = 0; d8 < 8; ++d8) {
                    bf16x8 b = *(const bf16x8*)
                        &Vb[(size_t)(d8 * 16 + l16) * 128 + (((wk * 4 + quad) ^ l16) * 8)];
                    o[0][d8] = __builtin_amdgcn_mfma_f32_16x16x32_bf16(
                        pa0, b, o[0][d8], 0, 0, 0);
                    o[1][d8] = __builtin_amdgcn_mfma_f32_16x16x32_bf16(
                        pa1, b, o[1][d8], 0, 0, 0);
                }
            }
            __builtin_amdgcn_s_setprio(0);
        }

        // ---- merge the four kv-quarters (max-free partials just add) ----
        __syncthreads();                       // all K/V/P reads done
        float* Ox = (float*)smem;              // [2][3][32][132] f32 = 101376 B
        float* Lx = (float*)(smem + 101376);   // [2][3][32][16]  f32 = 12288 B
        if (wk) {
            int base = (wq * 3 + wk - 1) * 32;
            #pragma unroll
            for (int m = 0; m < 2; ++m)
                #pragma unroll
                for (int d8 = 0; d8 < 8; ++d8)
                    #pragma unroll
                    for (int r = 0; r < 4; ++r)
                        Ox[(base + m * 16 + quad * 4 + r) * 132 + d8 * 16 + l16] = o[m][d8][r];
            #pragma unroll
            for (int m = 0; m < 2; ++m)
                #pragma unroll
                for (int r = 0; r < 4; ++r)
                    Lx[(base + m * 16 + quad * 4 + r) * 16 + l16] = lsum[m][r];
        }
        __syncthreads();
        if (wk == 0) {
            #pragma unroll
            for (int j = 0; j < 3; ++j)
                #pragma unroll
                for (int m = 0; m < 2; ++m)
                    #pragma unroll
                    for (int d8 = 0; d8 < 8; ++d8)
                        #pragma unroll
                        for (int r = 0; r < 4; ++r)
                            o[m][d8][r] += Ox[((wq * 3 + j) * 32 + m * 16 + quad * 4 + r) * 132
                                              + d8 * 16 + l16];
            #pragma unroll
            for (int m = 0; m < 2; ++m)
                #pragma unroll
                for (int r = 0; r < 4; ++r) {
                    #pragma unroll
                    for (int j = 0; j < 3; ++j)
                        lsum[m][r] += Lx[((wq * 3 + j) * 32 + m * 16 + quad * 4 + r) * 16 + l16];
                    #pragma unroll
                    for (int off = 1; off < 16; off <<= 1)
                        lsum[m][r] += __shfl_xor(lsum[m][r], off);
                    lsum[m][r] = 1.0f / lsum[m][r];
                }
            #pragma unroll
            for (int m = 0; m < 2; ++m)
                #pragma unroll
                for (int d8 = 0; d8 < 8; ++d8)
                    #pragma unroll
                    for (int r = 0; r < 4; ++r) {
                        int row = qbase + m * 16 + quad * 4 + r;
                        Out[(size_t)row * D_MODEL + h * HD + d8 * 16 + l16] =
                            f32_to_bf16(o[m][d8][r] * lsum[m][r]);
                    }
        }
    }
}

// ---------------------------------------------------------------------------
extern "C" void kernel_launch(void* const* d_in, const int* in_sizes, int n_in,
                              void* d_out, int out_size, void* d_ws, size_t ws_size,
                              hipStream_t stream)
{
    const float* hs  = (const float*)d_in[0];
    const float* Wq  = (const float*)d_in[1];
    const float* Wk  = (const float*)d_in[2];
    const float* Wv  = (const float*)d_in[3];
    const float* Wo  = (const float*)d_in[4];
    const float* Wr1 = (const float*)d_in[5];
    const float* br1 = (const float*)d_in[6];
    const float* Wr2 = (const float*)d_in[7];
    const float* br2 = (const float*)d_in[8];
    float* out = (float*)d_out;

    char* w = (char*)d_ws;
    const size_t MB = 1u << 20;
    float* l2_f     = (float*)(w + 0 * MB);    // 16 MB
    short* hs_bf    = (short*)(w + 16 * MB);   // 8 MB (aliased as attn_bf later)
    short* Wq_t     = (short*)(w + 24 * MB);   // 8 MB
    short* Wkv_t    = (short*)(w + 32 * MB);   // 4 MB  [Wk^T | Wv^T]
    short* Wr1_t    = (short*)(w + 36 * MB);   // 4 MB
    short* Wo_t     = (short*)(w + 40 * MB);   // 8 MB
    short* q_bf     = (short*)(w + 48 * MB);   // 8 MB
    short* h_bf     = (short*)(w + 56 * MB);   // 4 MB
    short* fused_bf = (short*)(w + 60 * MB);   // 8 MB
    short* kv_bf    = (short*)(w + 68 * MB);   // 4 MB
    short* qr       = (short*)(w + 72 * MB);   // 8 MB (H,T,HD), roped+scaled
    short* kr       = (short*)(w + 80 * MB);   // 2 MB (KVH,T,HD), roped
    short* vr       = (short*)(w + 82 * MB);   // 2 MB (KVH,HD,T)
    short* attn_bf  = hs_bf;                   // alias: hs_bf dead after q-gemm

    // weight transposes + EMA, one launch
    prep_kernel<<<12416, 256, 0, stream>>>(
        Wq, Wk, Wv, Wr1, Wo, hs, Wq_t, Wkv_t, Wr1_t, Wo_t, l2_f, hs_bf);

    // q = hs @ Wq : 16 x 32 = 512 blocks (2/CU)
    gemm_bt_kernel<128><<<dim3(16, 32), 256, 0, stream>>>(
        hs_bf, Wq_t, nullptr, q_bf, 2048, 2048, 2048, nullptr, 0);

    // h = silu(q @ Wr1 + br1) : BN=64 -> 16 x 32 = 512 blocks
    gemm_bt_kernel<64><<<dim3(16, 32), 256, 0, stream>>>(
        q_bf, Wr1_t, nullptr, h_bf, 2048, 1024, 2048, br1, 1);

    // fused = lam0*hs + lam1*l2 (router head recomputed per block)
    fuse_kernel<<<(T_SEQ * D_MODEL / 4) / 256, 256, 0, stream>>>(
        hs, l2_f, h_bf, Wr2, br2, fused_bf);

    // [k|v] = fused @ [Wk|Wv] : BN=64 -> 512 blocks
    gemm_bt_kernel<64><<<dim3(16, 32), 256, 0, stream>>>(
        fused_bf, Wkv_t, nullptr, kv_bf, 2048, 1024, 2048, nullptr, 0);

    // rope_q + rope_k + v-transpose in one launch
    pp_kernel<<<11264, 256, 0, stream>>>(q_bf, kv_bf, qr, kr, vr);

    // 8 waves = (2 q-subsets x 4 kv-quarters), paired phases, split-wait
    attn_kernel<<<dim3(NH, 16), 512, 0, stream>>>(qr, kr, vr, attn_bf);

    // out = attn @ Wo : 512 blocks
    gemm_bt_kernel<128><<<dim3(16, 32), 256, 0, stream>>>(
        attn_bf, Wo_t, out, nullptr, 2048, 2048, 2048, nullptr, 0);
}

// Round 12
// 294.061 us; speedup vs baseline: 1.0791x; 1.0791x over previous
//
#include <hip/hip_runtime.h>
#include <hip/hip_bf16.h>

#define T_SEQ 2048
#define D_MODEL 2048
#define NH 16
#define NKVH 4
#define HD 128

typedef __attribute__((ext_vector_type(8))) short bf16x8;
typedef __attribute__((ext_vector_type(4))) float f32x4;

static __device__ __forceinline__ short f32_to_bf16(float f) {
    unsigned u = __float_as_uint(f);
    u += 0x7fffu + ((u >> 16) & 1u);
    return (short)(u >> 16);
}
static __device__ __forceinline__ float bf16_to_f32(short s) {
    return __uint_as_float(((unsigned)(unsigned short)s) << 16);
}
static __device__ __forceinline__ void gl_to_lds16(const void* g, void* l) {
    __builtin_amdgcn_global_load_lds(
        (const __attribute__((address_space(1))) unsigned int*)g,
        (__attribute__((address_space(3))) unsigned int*)l, 16, 0, 0);
}

// ---------------------------------------------------------------------------
// Pipelined GEMM: R7 version verbatim (in best-measured 305.5 total).
// BM=64, 256 thr, 512 blocks = 2/CU; tbuf + counted vmcnt.
// ---------------------------------------------------------------------------
template<int BN>
__global__ __launch_bounds__(256, 2) void gemm_bt_kernel(
    const short* __restrict__ A, const short* __restrict__ Bt,
    float* __restrict__ Cf, short* __restrict__ Cb,
    int M, int N, int K, const float* __restrict__ bias, int act)
{
    constexpr int NI = BN / 64;                // 2 or 1
    constexpr int BCH = BN / 32;               // B staging instrs/wave (4 or 2)
    __shared__ short Alds[3][64 * 64];
    __shared__ short Blds[3][BN * 64];

    const int tid = threadIdx.x;
    const int wave = tid >> 6, lane = tid & 63;
    const int l16 = lane & 15, quad = lane >> 4;
    const int wn = wave * (BN / 4);
    const int m0 = blockIdx.y * 64, n0 = blockIdx.x * BN;
    const int niter = K >> 6;

    f32x4 acc[4][NI] = {};

    #pragma unroll
    for (int st = 0; st < 2; ++st) {
        int kk0 = st << 6;
        #pragma unroll
        for (int p = 0; p < 2; ++p) {
            int li = p * 256 + tid;
            int row = li >> 3, sc = li & 7;
            gl_to_lds16(A + (size_t)(m0 + row) * K + kk0 + ((sc ^ (row & 7)) * 8),
                        &Alds[st][(size_t)(p * 256 + wave * 64) * 8]);
        }
        #pragma unroll
        for (int p = 0; p < BCH; ++p) {
            int li = p * 256 + tid;
            int row = li >> 3, sc = li & 7;
            gl_to_lds16(Bt + (size_t)(n0 + row) * K + kk0 + ((sc ^ (row & 7)) * 8),
                        &Blds[st][(size_t)(p * 256 + wave * 64) * 8]);
        }
    }

    int cur = 0, stg = 2;
    for (int t = 0; t < niter; ++t) {
        if (t + 1 < niter) {
            if constexpr (BN == 128)
                asm volatile("s_waitcnt vmcnt(6)\n\ts_barrier" ::: "memory");
            else
                asm volatile("s_waitcnt vmcnt(4)\n\ts_barrier" ::: "memory");
        } else {
            asm volatile("s_waitcnt vmcnt(0)\n\ts_barrier" ::: "memory");
        }

        if (t + 2 < niter) {
            int k1 = (t + 2) << 6;
            #pragma unroll
            for (int p = 0; p < 2; ++p) {
                int li = p * 256 + tid;
                int row = li >> 3, sc = li & 7;
                gl_to_lds16(A + (size_t)(m0 + row) * K + k1 + ((sc ^ (row & 7)) * 8),
                            &Alds[stg][(size_t)(p * 256 + wave * 64) * 8]);
            }
            #pragma unroll
            for (int p = 0; p < BCH; ++p) {
                int li = p * 256 + tid;
                int row = li >> 3, sc = li & 7;
                gl_to_lds16(Bt + (size_t)(n0 + row) * K + k1 + ((sc ^ (row & 7)) * 8),
                            &Blds[stg][(size_t)(p * 256 + wave * 64) * 8]);
            }
        }

        const short* Ab = Alds[cur];
        const short* Bb = Blds[cur];
        #pragma unroll
        for (int kk = 0; kk < 2; ++kk) {
            bf16x8 a[4], b[NI];
            #pragma unroll
            for (int i = 0; i < 4; ++i)
                a[i] = *(const bf16x8*)
                    &Ab[(size_t)(i * 16 + l16) * 64 + (((kk * 4 + quad) ^ (l16 & 7)) * 8)];
            #pragma unroll
            for (int i = 0; i < NI; ++i)
                b[i] = *(const bf16x8*)
                    &Bb[(size_t)(wn + i * 16 + l16) * 64 + (((kk * 4 + quad) ^ (l16 & 7)) * 8)];
            #pragma unroll
            for (int mi = 0; mi < 4; ++mi)
                #pragma unroll
                for (int ni = 0; ni < NI; ++ni)
                    acc[mi][ni] = __builtin_amdgcn_mfma_f32_16x16x32_bf16(
                        a[mi], b[ni], acc[mi][ni], 0, 0, 0);
        }
        cur = (cur == 2) ? 0 : cur + 1;
        stg = (stg == 2) ? 0 : stg + 1;
    }

    #pragma unroll
    for (int mi = 0; mi < 4; ++mi) {
        #pragma unroll
        for (int ni = 0; ni < NI; ++ni) {
            int col = n0 + wn + ni * 16 + l16;
            float bv = bias ? bias[col] : 0.0f;
            #pragma unroll
            for (int r = 0; r < 4; ++r) {
                int row = m0 + mi * 16 + quad * 4 + r;
                float x = acc[mi][ni][r] + bv;
                if (act) x = x / (1.0f + __expf(-x));
                size_t o = (size_t)row * N + col;
                if (Cf) Cf[o] = x;
                if (Cb) Cb[o] = f32_to_bf16(x);
            }
        }
    }
}

// ---------------------------------------------------------------------------
// prep R12: weight transposes + EMA in one launch, EMA FIRST.
// R11 lesson: EMA blocks at the END of the grid ran as a serial tail on
// half the CUs (prep 58-63us, the longest kernel). Fix: (a) EMA = blocks
// [0,256) so its long-latency chains overlap the 12288 short transpose
// blocks; (b) EMA re-split to 32 t-tiles x 64 rows x 8 d-blocks = 256
// blocks (per-block work -1/3, parallelism 2x). Windowed warmup (192 rows,
// beta^192 ~ 2e-9) unchanged.
// ---------------------------------------------------------------------------
__global__ __launch_bounds__(256) void prep_kernel(
    const float* __restrict__ Wq, const float* __restrict__ Wk,
    const float* __restrict__ Wv, const float* __restrict__ Wr1,
    const float* __restrict__ Wo, const float* __restrict__ hs,
    short* __restrict__ Wq_t, short* __restrict__ Wkv_t,
    short* __restrict__ Wr1_t, short* __restrict__ Wo_t,
    float* __restrict__ l2, short* __restrict__ hs_b)
{
    __shared__ float tile[32][33];
    int b = blockIdx.x;
    if (b < 256) {                         // ---- windowed causal EMA ----
        int d = (b & 7) * 256 + threadIdx.x;
        int t0 = (b >> 3) * 64;
        int ts = t0 - 192; if (ts < 0) ts = 0;
        float m = 0.0f;
        for (int tb = ts; tb < t0; tb += 16) {
            float buf[16];
            #pragma unroll
            for (int j = 0; j < 16; ++j) buf[j] = hs[(size_t)(tb + j) * D_MODEL + d];
            #pragma unroll
            for (int j = 0; j < 16; ++j) m = 0.9f * m + 0.1f * buf[j];
        }
        for (int tb = t0; tb < t0 + 64; tb += 16) {
            float buf[16];
            #pragma unroll
            for (int j = 0; j < 16; ++j) buf[j] = hs[(size_t)(tb + j) * D_MODEL + d];
            #pragma unroll
            for (int j = 0; j < 16; ++j) hs_b[(size_t)(tb + j) * D_MODEL + d] = f32_to_bf16(buf[j]);
            #pragma unroll
            for (int j = 0; j < 16; ++j) { m = 0.9f * m + 0.1f * buf[j]; buf[j] = m; }
            #pragma unroll
            for (int j = 0; j < 16; ++j) l2[(size_t)(tb + j) * D_MODEL + d] = buf[j];
        }
    } else {                               // ---- weight transposes ----
        int bb = b - 256;
        int j = bb / 192, bx = bb - j * 192;
        const float* src; short* dst; int ld, cb;
        if (bx < 64)       { src = Wq;  dst = Wq_t;  ld = 2048; cb = bx; }
        else if (bx < 80)  { src = Wk;  dst = Wkv_t; ld = 512;  cb = bx - 64; }
        else if (bx < 96)  { src = Wv;  dst = Wkv_t + (size_t)512 * 2048; ld = 512; cb = bx - 80; }
        else if (bx < 128) { src = Wr1; dst = Wr1_t; ld = 1024; cb = bx - 96; }
        else               { src = Wo;  dst = Wo_t;  ld = 2048; cb = bx - 128; }
        int c0 = cb * 32, r0 = j * 32;
        int t = threadIdx.x;
        int r = t >> 3, c4 = (t & 7) * 4;
        float4 v = *(const float4*)&src[(size_t)(r0 + r) * ld + c0 + c4];
        tile[r][c4 + 0] = v.x; tile[r][c4 + 1] = v.y;
        tile[r][c4 + 2] = v.z; tile[r][c4 + 3] = v.w;
        __syncthreads();
        short o[4];
        #pragma unroll
        for (int q = 0; q < 4; ++q) o[q] = f32_to_bf16(tile[c4 + q][r]);
        *(uint2*)&dst[(size_t)(c0 + r) * 2048 + r0 + c4] = *(const uint2*)o;
    }
}

// ---------------------------------------------------------------------------
// fuse: router head folded in (R10). grid 4096 x 256thr.
// ---------------------------------------------------------------------------
__global__ __launch_bounds__(256) void fuse_kernel(
    const float* __restrict__ hs, const float* __restrict__ l2,
    const short* __restrict__ h, const float* __restrict__ Wr2,
    const float* __restrict__ br2, short* __restrict__ fused)
{
    const int tid = threadIdx.x;
    const int t = blockIdx.x >> 1;

    float z0 = 0.0f, z1 = 0.0f;
    {
        const short* hr = h + (size_t)t * 1024;
        short4 hv4 = *(const short4*)&hr[tid * 4];
        const float2* w2 = (const float2*)Wr2;
        #pragma unroll
        for (int j = 0; j < 4; ++j) {
            float hv = bf16_to_f32(((const short*)&hv4)[j]);
            float2 w = w2[tid * 4 + j];
            z0 += hv * w.x;
            z1 += hv * w.y;
        }
    }
    #pragma unroll
    for (int off = 1; off < 64; off <<= 1) {
        z0 += __shfl_xor(z0, off);
        z1 += __shfl_xor(z1, off);
    }
    __shared__ float red[2][4];
    int wave = tid >> 6, lane = tid & 63;
    if (lane == 0) { red[0][wave] = z0; red[1][wave] = z1; }
    __syncthreads();
    z0 = red[0][0] + red[0][1] + red[0][2] + red[0][3] + br2[0];
    z1 = red[1][0] + red[1][1] + red[1][2] + red[1][3] + br2[1];
    float mx = fmaxf(z0, z1);
    float e0 = expf(z0 - mx), e1 = expf(z1 - mx);
    float inv = 1.0f / (e0 + e1);
    float a0 = e0 * inv, a1 = e1 * inv;

    int idx = blockIdx.x * 256 + tid;
    float4 a = ((const float4*)hs)[idx];
    float4 b = ((const float4*)l2)[idx];
    short o[4] = {f32_to_bf16(a0 * a.x + a1 * b.x), f32_to_bf16(a0 * a.y + a1 * b.y),
                  f32_to_bf16(a0 * a.z + a1 * b.z), f32_to_bf16(a0 * a.w + a1 * b.w)};
    *(uint2*)(fused + (size_t)idx * 4) = *(const uint2*)o;
}

// ---------------------------------------------------------------------------
// rope_q + rope_k + V-transpose in one launch (R10).
// ---------------------------------------------------------------------------
__global__ __launch_bounds__(256) void pp_kernel(
    const short* __restrict__ q, const short* __restrict__ kv,
    short* __restrict__ qr, short* __restrict__ kr, short* __restrict__ vr)
{
    int bx = blockIdx.x;
    if (bx < 8192) {                       // RoPE q, 1/sqrt(HD) folded in
        int idx = bx * 256 + threadIdx.x;
        int d = idx & 63;
        int h = (idx >> 6) & 15;
        int t = idx >> 10;
        float fr = (float)t * __expf(-(float)d * 0.14391156831212787f);
        float s, c;
        sincosf(fr, &s, &c);
        const float sc = 0.08838834764831845f;
        const short* src = q + (size_t)t * D_MODEL + h * HD;
        float x1 = bf16_to_f32(src[d]) * sc, x2 = bf16_to_f32(src[d + 64]) * sc;
        short* dst = qr + ((size_t)h * T_SEQ + t) * HD;
        dst[d]      = f32_to_bf16(x1 * c - x2 * s);
        dst[d + 64] = f32_to_bf16(x2 * c + x1 * s);
    } else if (bx < 10240) {               // RoPE k
        int idx = (bx - 8192) * 256 + threadIdx.x;
        int d = idx & 63;
        int kh = (idx >> 6) & 3;
        int t = idx >> 8;
        float fr = (float)t * __expf(-(float)d * 0.14391156831212787f);
        float s, c;
        sincosf(fr, &s, &c);
        const short* src = kv + (size_t)t * 1024 + kh * HD;
        float x1 = bf16_to_f32(src[d]), x2 = bf16_to_f32(src[d + 64]);
        short* dst = kr + ((size_t)kh * T_SEQ + t) * HD;
        dst[d]      = f32_to_bf16(x1 * c - x2 * s);
        dst[d + 64] = f32_to_bf16(x2 * c + x1 * s);
    } else {                               // bf16 transpose of v half of kv
        __shared__ float tile[32][33];
        int b2 = bx - 10240;
        int c0 = (b2 & 15) * 32, r0 = (b2 >> 4) * 32;
        const short* src = kv + 512;
        int x = threadIdx.x & 31, y = threadIdx.x >> 5;
        #pragma unroll
        for (int i = 0; i < 4; ++i)
            tile[y + i * 8][x] = bf16_to_f32(src[(size_t)(r0 + y + i * 8) * 1024 + c0 + x]);
        __syncthreads();
        #pragma unroll
        for (int i = 0; i < 4; ++i)
            vr[(size_t)(c0 + y + i * 8) * 2048 + r0 + x] = f32_to_bf16(tile[x][y + i * 8]);
    }
}

// ---------------------------------------------------------------------------
// Causal flash attention: R10 version verbatim (43.8 us measured).
// R11 lesson: split-wait (second per-iter barrier) did not help -- reverted.
// Balanced two-phase pairing, 17 uniform iters, 2 q-subsets x 4 kv-quarters,
// LDS-staged K/V, padded P [32][40], V-frag hoist before softmax.
// ---------------------------------------------------------------------------
__global__ __launch_bounds__(512, 2) void attn_kernel(
    const short* __restrict__ Qr, const short* __restrict__ Kr,
    const short* __restrict__ Vt, short* __restrict__ Out)
{
    const int h = blockIdx.x;           // 0..15  (fast dim -> XCD spread)
    const int y = blockIdx.y;           // 0..15, pair index
    const int kvh = h >> 2;
    const int tid = threadIdx.x;
    const int wave = tid >> 6, lane = tid & 63;
    const int l16 = lane & 15, quad = lane >> 4;
    const int wq = wave & 1;            // q-subset (32 rows)
    const int wk = wave >> 1;           // kv-quarter (32 cols)

    __shared__ __align__(16) char smem[151552];
    short* Klds = (short*)smem;               // [2][128*128]  64 KB
    short* Vlds = (short*)(smem + 65536);     // [2][128*128]  64 KB
    short* Plds = (short*)(smem + 131072);    // [8][32][40]   20 KB, padded

    const short* kbase = Kr + (size_t)kvh * T_SEQ * HD;
    const short* vbase = Vt + (size_t)kvh * HD * T_SEQ;

    #pragma unroll 1
    for (int ph = 0; ph < 2; ++ph) {
        const int qt32 = ph ? (31 - y) : y;        // 64-row tile index
        const int qbase = qt32 * 64 + wq * 32;
        const int n = (qt32 >> 1) + 1;             // KV-128 tiles needed
        const int ko = wk * 32;                    // this wave's kv-quarter

        bf16x8 qf[2][4];
        #pragma unroll
        for (int m = 0; m < 2; ++m) {
            const short* qrow = Qr + ((size_t)h * T_SEQ + qbase + m * 16 + l16) * HD;
            #pragma unroll
            for (int kc = 0; kc < 4; ++kc)
                qf[m][kc] = *(const bf16x8*)&qrow[kc * 32 + quad * 8];
        }
        f32x4 o[2][8] = {};
        float lsum[2][4] = {};

        __syncthreads();   // LDS free (ph0: init; ph1: merge readers done)

        {   // stage tile 0 -> buf 0 (proven addressing, 512 threads)
            #pragma unroll
            for (int p = 0; p < 4; ++p) {
                int li = p * 512 + tid;
                int row = li >> 4, gs = (li & 15) ^ (row & 15);
                gl_to_lds16(kbase + (size_t)row * HD + gs * 8,
                            &Klds[(size_t)(p * 512 + wave * 64) * 8]);
            }
            #pragma unroll
            for (int p = 0; p < 4; ++p) {
                int li = p * 512 + tid;
                int row = li >> 4, gs = (li & 15) ^ (row & 15);
                gl_to_lds16(vbase + (size_t)row * T_SEQ + gs * 8,
                            &Vlds[(size_t)(p * 512 + wave * 64) * 8]);
            }
        }

        for (int t = 0; t < n; ++t) {
            asm volatile("s_waitcnt vmcnt(0)\n\ts_barrier" ::: "memory");

            if (t + 1 < n) {   // prefetch next KV-128 tile
                int kv1 = (t + 1) << 7;
                int nb = (t + 1) & 1;
                const short* ks = kbase + (size_t)kv1 * HD;
                #pragma unroll
                for (int p = 0; p < 4; ++p) {
                    int li = p * 512 + tid;
                    int row = li >> 4, gs = (li & 15) ^ (row & 15);
                    gl_to_lds16(ks + (size_t)row * HD + gs * 8,
                                &Klds[(size_t)(nb * 16384 + (p * 512 + wave * 64) * 8)]);
                }
                #pragma unroll
                for (int p = 0; p < 4; ++p) {
                    int li = p * 512 + tid;
                    int row = li >> 4, gs = (li & 15) ^ (row & 15);
                    gl_to_lds16(vbase + (size_t)row * T_SEQ + kv1 + gs * 8,
                                &Vlds[(size_t)(nb * 16384 + (p * 512 + wave * 64) * 8)]);
                }
            }

            const short* Kb = Klds + (size_t)(t & 1) * 16384;
            const short* Vb = Vlds + (size_t)(t & 1) * 16384;

            // QK^T: 32 q-rows x this wave's 32 kv cols
            f32x4 s[2][2];
            #pragma unroll
            for (int m = 0; m < 2; ++m)
                #pragma unroll
                for (int ni = 0; ni < 2; ++ni) s[m][ni] = (f32x4){0, 0, 0, 0};
            __builtin_amdgcn_s_setprio(1);
            #pragma unroll
            for (int ni = 0; ni < 2; ++ni)
                #pragma unroll
                for (int kc = 0; kc < 4; ++kc) {
                    bf16x8 b = *(const bf16x8*)
                        &Kb[(size_t)(ko + ni * 16 + l16) * 128 + (((kc * 4 + quad) ^ l16) * 8)];
                    s[0][ni] = __builtin_amdgcn_mfma_f32_16x16x32_bf16(qf[0][kc], b, s[0][ni], 0, 0, 0);
                    s[1][ni] = __builtin_amdgcn_mfma_f32_16x16x32_bf16(qf[1][kc], b, s[1][ni], 0, 0, 0);
                }
            __builtin_amdgcn_s_setprio(0);

            // V fragments: issue NOW so latency hides under the softmax
            bf16x8 vb[8];
            #pragma unroll
            for (int d8 = 0; d8 < 8; ++d8)
                vb[d8] = *(const bf16x8*)
                    &Vb[(size_t)(d8 * 16 + l16) * 128 + (((wk * 4 + quad) ^ l16) * 8)];

            // softmax (max-free) -> padded P [32][40]
            short* Pw = Plds + wave * 1280;
            if (t == n - 1) {
                int kvg0 = (t << 7) + ko;
                #pragma unroll
                for (int m = 0; m < 2; ++m)
                    #pragma unroll
                    for (int ni = 0; ni < 2; ++ni) {
                        int kvg = kvg0 + ni * 16 + l16;
                        #pragma unroll
                        for (int r = 0; r < 4; ++r) {
                            int qg = qbase + m * 16 + quad * 4 + r;
                            float p = (kvg <= qg) ? __expf(s[m][ni][r]) : 0.0f;
                            lsum[m][r] += p;
                            Pw[(m * 16 + quad * 4 + r) * 40 + ni * 16 + l16] =
                                f32_to_bf16(p);
                        }
                    }
            } else {
                #pragma unroll
                for (int m = 0; m < 2; ++m)
                    #pragma unroll
                    for (int ni = 0; ni < 2; ++ni)
                        #pragma unroll
                        for (int r = 0; r < 4; ++r) {
                            float p = __expf(s[m][ni][r]);
                            lsum[m][r] += p;
                            Pw[(m * 16 + quad * 4 + r) * 40 + ni * 16 + l16] =
                                f32_to_bf16(p);
                        }
            }
            asm volatile("s_waitcnt lgkmcnt(0)" ::: "memory");

            // PV: V-frag (already in regs) feeds 2 row-groups
            __builtin_amdgcn_s_setprio(1);
            {
                bf16x8 pa0 = *(const bf16x8*)&Pw[l16 * 40 + quad * 8];
                bf16x8 pa1 = *(const bf16x8*)&Pw[(16 + l16) * 40 + quad * 8];
                #pragma unroll
                for (int d8 = 0; d8 < 8; ++d8) {
                    o[0][d8] = __builtin_amdgcn_mfma_f32_16x16x32_bf16(
                        pa0, vb[d8], o[0][d8], 0, 0, 0);
                    o[1][d8] = __builtin_amdgcn_mfma_f32_16x16x32_bf16(
                        pa1, vb[d8], o[1][d8], 0, 0, 0);
                }
            }
            __builtin_amdgcn_s_setprio(0);
        }

        // ---- merge the four kv-quarters (max-free partials just add) ----
        __syncthreads();                       // all K/V/P reads done
        float* Ox = (float*)smem;              // [2][3][32][132] f32 = 101376 B
        float* Lx = (float*)(smem + 101376);   // [2][3][32][16]  f32 = 12288 B
        if (wk) {
            int base = (wq * 3 + wk - 1) * 32;
            #pragma unroll
            for (int m = 0; m < 2; ++m)
                #pragma unroll
                for (int d8 = 0; d8 < 8; ++d8)
                    #pragma unroll
                    for (int r = 0; r < 4; ++r)
                        Ox[(base + m * 16 + quad * 4 + r) * 132 + d8 * 16 + l16] = o[m][d8][r];
            #pragma unroll
            for (int m = 0; m < 2; ++m)
                #pragma unroll
                for (int r = 0; r < 4; ++r)
                    Lx[(base + m * 16 + quad * 4 + r) * 16 + l16] = lsum[m][r];
        }
        __syncthreads();
        if (wk == 0) {
            #pragma unroll
            for (int j = 0; j < 3; ++j)
                #pragma unroll
                for (int m = 0; m < 2; ++m)
                    #pragma unroll
                    for (int d8 = 0; d8 < 8; ++d8)
                        #pragma unroll
                        for (int r = 0; r < 4; ++r)
                            o[m][d8][r] += Ox[((wq * 3 + j) * 32 + m * 16 + quad * 4 + r) * 132
                                              + d8 * 16 + l16];
            #pragma unroll
            for (int m = 0; m < 2; ++m)
                #pragma unroll
                for (int r = 0; r < 4; ++r) {
                    #pragma unroll
                    for (int j = 0; j < 3; ++j)
                        lsum[m][r] += Lx[((wq * 3 + j) * 32 + m * 16 + quad * 4 + r) * 16 + l16];
                    #pragma unroll
                    for (int off = 1; off < 16; off <<= 1)
                        lsum[m][r] += __shfl_xor(lsum[m][r], off);
                    lsum[m][r] = 1.0f / lsum[m][r];
                }
            #pragma unroll
            for (int m = 0; m < 2; ++m)
                #pragma unroll
                for (int d8 = 0; d8 < 8; ++d8)
                    #pragma unroll
                    for (int r = 0; r < 4; ++r) {
                        int row = qbase + m * 16 + quad * 4 + r;
                        Out[(size_t)row * D_MODEL + h * HD + d8 * 16 + l16] =
                            f32_to_bf16(o[m][d8][r] * lsum[m][r]);
                    }
        }
    }
}

// ---------------------------------------------------------------------------
extern "C" void kernel_launch(void* const* d_in, const int* in_sizes, int n_in,
                              void* d_out, int out_size, void* d_ws, size_t ws_size,
                              hipStream_t stream)
{
    const float* hs  = (const float*)d_in[0];
    const float* Wq  = (const float*)d_in[1];
    const float* Wk  = (const float*)d_in[2];
    const float* Wv  = (const float*)d_in[3];
    const float* Wo  = (const float*)d_in[4];
    const float* Wr1 = (const float*)d_in[5];
    const float* br1 = (const float*)d_in[6];
    const float* Wr2 = (const float*)d_in[7];
    const float* br2 = (const float*)d_in[8];
    float* out = (float*)d_out;

    char* w = (char*)d_ws;
    const size_t MB = 1u << 20;
    float* l2_f     = (float*)(w + 0 * MB);    // 16 MB
    short* hs_bf    = (short*)(w + 16 * MB);   // 8 MB (aliased as attn_bf later)
    short* Wq_t     = (short*)(w + 24 * MB);   // 8 MB
    short* Wkv_t    = (short*)(w + 32 * MB);   // 4 MB  [Wk^T | Wv^T]
    short* Wr1_t    = (short*)(w + 36 * MB);   // 4 MB
    short* Wo_t     = (short*)(w + 40 * MB);   // 8 MB
    short* q_bf     = (short*)(w + 48 * MB);   // 8 MB
    short* h_bf     = (short*)(w + 56 * MB);   // 4 MB
    short* fused_bf = (short*)(w + 60 * MB);   // 8 MB
    short* kv_bf    = (short*)(w + 68 * MB);   // 4 MB
    short* qr       = (short*)(w + 72 * MB);   // 8 MB (H,T,HD), roped+scaled
    short* kr       = (short*)(w + 80 * MB);   // 2 MB (KVH,T,HD), roped
    short* vr       = (short*)(w + 82 * MB);   // 2 MB (KVH,HD,T)
    short* attn_bf  = hs_bf;                   // alias: hs_bf dead after q-gemm

    // EMA (blocks 0..255, dispatched first) + weight transposes, one launch
    prep_kernel<<<12544, 256, 0, stream>>>(
        Wq, Wk, Wv, Wr1, Wo, hs, Wq_t, Wkv_t, Wr1_t, Wo_t, l2_f, hs_bf);

    // q = hs @ Wq : 16 x 32 = 512 blocks (2/CU)
    gemm_bt_kernel<128><<<dim3(16, 32), 256, 0, stream>>>(
        hs_bf, Wq_t, nullptr, q_bf, 2048, 2048, 2048, nullptr, 0);

    // h = silu(q @ Wr1 + br1) : BN=64 -> 16 x 32 = 512 blocks
    gemm_bt_kernel<64><<<dim3(16, 32), 256, 0, stream>>>(
        q_bf, Wr1_t, nullptr, h_bf, 2048, 1024, 2048, br1, 1);

    // fused = lam0*hs + lam1*l2 (router head recomputed per block)
    fuse_kernel<<<(T_SEQ * D_MODEL / 4) / 256, 256, 0, stream>>>(
        hs, l2_f, h_bf, Wr2, br2, fused_bf);

    // [k|v] = fused @ [Wk|Wv] : BN=64 -> 512 blocks
    gemm_bt_kernel<64><<<dim3(16, 32), 256, 0, stream>>>(
        fused_bf, Wkv_t, nullptr, kv_bf, 2048, 1024, 2048, nullptr, 0);

    // rope_q + rope_k + v-transpose in one launch
    pp_kernel<<<11264, 256, 0, stream>>>(q_bf, kv_bf, qr, kr, vr);

    // 8 waves = (2 q-subsets x 4 kv-quarters), two balanced phases (y, 31-y)
    attn_kernel<<<dim3(NH, 16), 512, 0, stream>>>(qr, kr, vr, attn_bf);

    // out = attn @ Wo : 512 blocks
    gemm_bt_kernel<128><<<dim3(16, 32), 256, 0, stream>>>(
        attn_bf, Wo_t, out, nullptr, 2048, 2048, 2048, nullptr, 0);
}